// Round 8
// baseline (447.954 us; speedup 1.0000x reference)
//
#include <hip/hip_runtime.h>

// TargetOpinionPairRepresentation on MI355X — R8: address-ordered writes.
//
// out[b, t*64+o] = concat(spans[b,T[b,t]] (768f), spans[b,Op[b,o]] (768f),
//                         dist_emb[bucket] (128f))
//
// R7 post-mortem: kernel ~150-160us vs ~75us floor; nt-store / reg-reuse /
// XCD swizzle all ~neutral. Theory: writes leave L2 as 1KB-granular
// scattered bursts (j-stride 6.5KB x 7000 waves) -> ~50% DRAM efficiency.
// R8: block = 32 CONSECUTIVE output rows (one 213KB contiguous slab),
// written sequentially; each wave walks its rows left->right in 1KB steps.
// Target row hoisted to registers (block-uniform t); opinion row gathered
// coalesced per row (L2-hot); bucket row-uniform (scalar path).

#define B_DIM 16
#define S_DIM 512
#define D_DIM 768
#define E_DIM 128
#define T_DIM 64
#define O_DIM 64
#define ROW_FLOATS (2 * D_DIM + E_DIM)   // 1664
#define ROWS_PER_BLOCK 32
#define N_BLOCKS (B_DIM * T_DIM * O_DIM / ROWS_PER_BLOCK)  // 2048

typedef float f32x4 __attribute__((ext_vector_type(4)));

__global__ __launch_bounds__(256) void pair_rep_seq(
    const float* __restrict__ spans,           // [B,S,D]
    const float* __restrict__ dist_emb,        // [14,E]
    const int*   __restrict__ span_indices,    // [S,2]
    const int*   __restrict__ target_indices,  // [B,T]
    const int*   __restrict__ opinion_indices, // [B,O]
    float*       __restrict__ out)             // [B,4096,1664]
{
    // XCD-bijective swizzle (2048 % 8 == 0): XCD x owns logical blocks
    // [x*256, (x+1)*256) = a contiguous 54.5MB eighth of the output.
    const int blk0 = blockIdx.x;                  // 0..2047
    const int blk  = (blk0 & 7) * (N_BLOCKS / 8) + (blk0 >> 3);

    const int b  = blk >> 7;                      // 128 blocks per batch
    const int r0 = (blk & 127) * ROWS_PER_BLOCK;  // start row within batch
    const int t  = r0 >> 6;                       // block-uniform (32 | 64)
    const int wave = threadIdx.x >> 6;
    const int lane = threadIdx.x & 63;

    const int ti  = target_indices[b * T_DIM + t];
    const int ab0 = span_indices[2 * ti];
    const int ab1 = span_indices[2 * ti + 1];

    // Hoist the target row (3KB) into 3 regs per lane — reused by all rows.
    const f32x4* trow = (const f32x4*)(spans + ((size_t)b * S_DIM + ti) * D_DIM);
    const f32x4 t0 = trow[lane];
    const f32x4 t1 = trow[64 + lane];
    const f32x4 t2 = trow[128 + lane];

    const int bins[14] = {0, 1, 2, 3, 4, 5, 7, 8, 15, 16, 31, 32, 63, 64};

    for (int rr = wave; rr < ROWS_PER_BLOCK; rr += 4) {
        const int r  = r0 + rr;                   // row within batch
        const int o  = r & 63;
        const int oi = opinion_indices[b * O_DIM + o];   // wave-uniform
        const int c0 = span_indices[2 * oi];
        const int d0 = span_indices[2 * oi + 1];
        const int width = min(abs(ab1 - c0), abs(ab0 - d0));
        int bucket = -1;
#pragma unroll
        for (int k = 0; k < 14; ++k) bucket += (width >= bins[k]) ? 1 : 0;

        const f32x4* orow = (const f32x4*)(spans + ((size_t)b * S_DIM + oi) * D_DIM);
        float* dst = out + ((size_t)b * 4096 + r) * ROW_FLOATS;

        // Sequential 1KB steps across the row: t0,t1,t2 | o0,o1,o2 | dist.
        const f32x4 o0 = orow[lane];
        const f32x4 o1 = orow[64 + lane];
        const f32x4 o2 = orow[128 + lane];
        *(f32x4*)(dst + (size_t)lane * 4)            = t0;
        *(f32x4*)(dst + (size_t)(64 + lane) * 4)     = t1;
        *(f32x4*)(dst + (size_t)(128 + lane) * 4)    = t2;
        *(f32x4*)(dst + (size_t)(192 + lane) * 4)    = o0;
        *(f32x4*)(dst + (size_t)(256 + lane) * 4)    = o1;
        *(f32x4*)(dst + (size_t)(320 + lane) * 4)    = o2;
        if (lane < 32) {
            const f32x4 dv = ((const f32x4*)(dist_emb + (size_t)bucket * E_DIM))[lane];
            *(f32x4*)(dst + (size_t)(384 + lane) * 4) = dv;
        }
    }
}

extern "C" void kernel_launch(void* const* d_in, const int* in_sizes, int n_in,
                              void* d_out, int out_size, void* d_ws, size_t ws_size,
                              hipStream_t stream) {
    const float* spans           = (const float*)d_in[0];
    const float* dist_emb        = (const float*)d_in[1];
    const int*   span_indices    = (const int*)d_in[2];
    const int*   target_indices  = (const int*)d_in[3];
    const int*   opinion_indices = (const int*)d_in[4];
    float* out = (float*)d_out;

    pair_rep_seq<<<N_BLOCKS, 256, 0, stream>>>(
        spans, dist_emb, span_indices, target_indices, opinion_indices, out);
}